// Round 18
// baseline (186.195 us; speedup 1.0000x reference)
//
#include <hip/hip_runtime.h>
#include <math.h>

#define NN 50000
#define D 128
#define NBUK 256   // dst buckets (dst>>8), covers 65536 >= N
#define EPB 4096   // edges per block in bucket passes
#define SH_STRIDE 136

typedef __attribute__((ext_vector_type(8))) short bf16x8;
typedef __attribute__((ext_vector_type(4))) float f32x4;
typedef __attribute__((ext_vector_type(2))) float f32x2;

__device__ __forceinline__ float bf2f(unsigned short u) {
    union { unsigned int i; float f; } c;
    c.i = ((unsigned int)u) << 16;
    return c.f;
}
__device__ __forceinline__ unsigned short f2bf(float f) {
    union { float f; unsigned int i; } c;
    c.f = f;
    unsigned int u = c.i;
    return (unsigned short)((u + 0x7FFFu + ((u >> 16) & 1u)) >> 16);
}
__device__ __forceinline__ unsigned char f2f8(float v) {
    return (unsigned char)(__builtin_amdgcn_cvt_pk_fp8_f32(v, v, 0, false) & 0xFF);
}

// ---- merged: weight pack (6 layer W + Wfc) + x fp32->bf16+fp8 + zero ----
// blocks [0,384): layer weights; [384,408): Wfc pack (+bukcnt zero in 384);
// [408, ...): x convert.

__global__ __launch_bounds__(256) void cvtpack_kernel(const float* __restrict__ x,
                                                      unsigned short* __restrict__ xb,
                                                      unsigned int* __restrict__ x8,
                                                      int n4,
                                                      const float* __restrict__ W0,
                                                      const float* __restrict__ W1,
                                                      const float* __restrict__ W2,
                                                      const float* __restrict__ W3,
                                                      const float* __restrict__ W4,
                                                      const float* __restrict__ W5,
                                                      unsigned short* __restrict__ P,
                                                      const float* __restrict__ Wfc,
                                                      unsigned short* __restrict__ Pfc,
                                                      int* __restrict__ bukcnt) {
    if (blockIdx.x < 384) {
        int i = blockIdx.x * 256 + threadIdx.x;   // 0..98303
        int w = i >> 14, j = i & 16383;
        const float* W = (w == 0) ? W0 : (w == 1) ? W1 : (w == 2) ? W2
                       : (w == 3) ? W3 : (w == 4) ? W4 : W5;
        int e = j & 7, l = (j >> 3) & 63, n = (j >> 9) & 7, ks = j >> 12;
        int k = ks * 32 + (l >> 4) * 8 + e;
        int col = n * 16 + (l & 15);
        P[i] = f2bf(W[k * D + col]);
    } else if (blockIdx.x < 408) {
        if (blockIdx.x == 384) bukcnt[threadIdx.x] = 0;
        int i = (blockIdx.x - 384) * 256 + threadIdx.x;   // 0..6143
        int e = i & 7, l = (i >> 3) & 63, f = i >> 9;      // f = ks*3+n
        int ks = f / 3, n = f - ks * 3;
        int k = ks * 32 + (l >> 4) * 8 + e;
        int col = n * 16 + (l & 15);
        Pfc[i] = (col < 40) ? f2bf(Wfc[k * 40 + col]) : (unsigned short)0;
    } else {
        int i = (blockIdx.x - 408) * 256 + threadIdx.x;
        if (i < n4) {
            float4 v = ((const float4*)x)[i];
            ushort4 o;
            o.x = f2bf(v.x); o.y = f2bf(v.y); o.z = f2bf(v.z); o.w = f2bf(v.w);
            ((ushort4*)xb)[i] = o;
            unsigned int p01 = __builtin_amdgcn_cvt_pk_fp8_f32(v.x, v.y, 0, false);
            unsigned int p23 = __builtin_amdgcn_cvt_pk_fp8_f32(v.z, v.w, 0, false);
            x8[i] = (p01 & 0xFFFFu) | (p23 << 16);
        }
    }
}

// ---- bucketed CSR build -------------------------------------------------

__global__ __launch_bounds__(256) void bucket_hist_kernel(const int* __restrict__ e, int E,
                                                          int* __restrict__ bukcnt) {
    __shared__ int h[NBUK];
    int t = threadIdx.x;
    h[t] = 0;
    __syncthreads();
    int base = blockIdx.x * EPB;
    #pragma unroll
    for (int k = 0; k < 4; ++k) {
        int idx = base + k * 1024 + t * 4;
        if (idx + 4 <= E) {
            int4 d = *(const int4*)(e + E + idx);
            atomicAdd(&h[d.x >> 8], 1);
            atomicAdd(&h[d.y >> 8], 1);
            atomicAdd(&h[d.z >> 8], 1);
            atomicAdd(&h[d.w >> 8], 1);
        } else {
            for (int i = idx; i < E; ++i) atomicAdd(&h[e[E + i] >> 8], 1);
        }
    }
    __syncthreads();
    if (h[t]) atomicAdd(&bukcnt[t], h[t]);
}

__global__ __launch_bounds__(256) void bucket_scan_kernel(const int* __restrict__ bukcnt,
                                                          int* __restrict__ bukbase,
                                                          int* __restrict__ bukfill, int E) {
    __shared__ int wsum[4], woff[4];
    int t = threadIdx.x;
    int lane = t & 63, wave = t >> 6;
    int v = bukcnt[t];
    int incl = v;
    for (int off = 1; off < 64; off <<= 1) {
        int u = __shfl_up(incl, off);
        if (lane >= off) incl += u;
    }
    if (lane == 63) wsum[wave] = incl;
    __syncthreads();
    if (t == 0) {
        int r = 0;
        #pragma unroll
        for (int w = 0; w < 4; ++w) { woff[w] = r; r += wsum[w]; }
    }
    __syncthreads();
    int excl = woff[wave] + incl - v;
    bukbase[t] = excl;
    bukfill[t] = excl;
    if (t == 255) bukbase[NBUK] = E;
}

__global__ __launch_bounds__(256) void bucket_scatter_kernel(const int* __restrict__ e, int E,
                                                             int* __restrict__ bukfill,
                                                             unsigned int* __restrict__ ebuk) {
    __shared__ int h[NBUK];
    __shared__ int res[NBUK];
    int t = threadIdx.x;
    h[t] = 0;
    __syncthreads();
    int base = blockIdx.x * EPB;
    int4 d[4];
    #pragma unroll
    for (int k = 0; k < 4; ++k) {
        int idx = base + k * 1024 + t * 4;
        if (idx + 4 <= E) {
            d[k] = *(const int4*)(e + E + idx);
        } else {
            d[k].x = (idx + 0 < E) ? e[E + idx + 0] : -1;
            d[k].y = (idx + 1 < E) ? e[E + idx + 1] : -1;
            d[k].z = (idx + 2 < E) ? e[E + idx + 2] : -1;
            d[k].w = (idx + 3 < E) ? e[E + idx + 3] : -1;
        }
        if (d[k].x >= 0) atomicAdd(&h[d[k].x >> 8], 1);
        if (d[k].y >= 0) atomicAdd(&h[d[k].y >> 8], 1);
        if (d[k].z >= 0) atomicAdd(&h[d[k].z >> 8], 1);
        if (d[k].w >= 0) atomicAdd(&h[d[k].w >> 8], 1);
    }
    __syncthreads();
    res[t] = h[t] ? atomicAdd(&bukfill[t], h[t]) : 0;
    h[t] = 0;
    __syncthreads();
    #pragma unroll
    for (int k = 0; k < 4; ++k) {
        int idx = base + k * 1024 + t * 4;
        int4 s;
        if (idx + 4 <= E) {
            s = *(const int4*)(e + idx);
        } else {
            s.x = (idx + 0 < E) ? e[idx + 0] : 0;
            s.y = (idx + 1 < E) ? e[idx + 1] : 0;
            s.z = (idx + 2 < E) ? e[idx + 2] : 0;
            s.w = (idx + 3 < E) ? e[idx + 3] : 0;
        }
        if (d[k].x >= 0) { int b = d[k].x >> 8; int r = atomicAdd(&h[b], 1);
            ebuk[res[b] + r] = (unsigned int)(s.x & 0xFFFF) | ((unsigned int)(d[k].x & 255) << 16); }
        if (d[k].y >= 0) { int b = d[k].y >> 8; int r = atomicAdd(&h[b], 1);
            ebuk[res[b] + r] = (unsigned int)(s.y & 0xFFFF) | ((unsigned int)(d[k].y & 255) << 16); }
        if (d[k].z >= 0) { int b = d[k].z >> 8; int r = atomicAdd(&h[b], 1);
            ebuk[res[b] + r] = (unsigned int)(s.z & 0xFFFF) | ((unsigned int)(d[k].z & 255) << 16); }
        if (d[k].w >= 0) { int b = d[k].w >> 8; int r = atomicAdd(&h[b], 1);
            ebuk[res[b] + r] = (unsigned int)(s.w & 0xFFFF) | ((unsigned int)(d[k].w & 255) << 16); }
    }
}

// fused: per-bucket histogram + scan -> row_ptr/inv_cnt, then scatter
// csr_src using the in-LDS row pointers (same block = same bucket).

__global__ __launch_bounds__(256) void cnt_scan_scatter_kernel(const unsigned int* __restrict__ ebuk,
                                                               const int* __restrict__ bukbase,
                                                               int* __restrict__ row_ptr,
                                                               float* __restrict__ inv_cnt,
                                                               unsigned short* __restrict__ csr_src,
                                                               int N, int E) {
    __shared__ int c[NBUK];
    __shared__ int rp[NBUK];
    __shared__ int wsum[4], woff[4];
    int t = threadIdx.x, b = blockIdx.x;
    c[t] = 0;
    __syncthreads();
    int lo = bukbase[b], hi = bukbase[b + 1];
    for (int i = lo + t; i < hi; i += 256) atomicAdd(&c[ebuk[i] >> 16], 1);
    __syncthreads();
    int v = c[t];
    int lane = t & 63, wave = t >> 6;
    int incl = v;
    for (int off = 1; off < 64; off <<= 1) {
        int u = __shfl_up(incl, off);
        if (lane >= off) incl += u;
    }
    if (lane == 63) wsum[wave] = incl;
    __syncthreads();
    if (t == 0) {
        int r = 0;
        #pragma unroll
        for (int w = 0; w < 4; ++w) { woff[w] = r; r += wsum[w]; }
    }
    __syncthreads();
    int excl = woff[wave] + incl - v;
    rp[t] = bukbase[b] + excl;
    c[t] = 0;   // reuse as per-node fill counter
    int g = b * NBUK + t;
    if (g < N) {
        row_ptr[g] = rp[t];
        inv_cnt[g] = 1.0f / fmaxf((float)v, 1.0f);
    }
    if (g == N) row_ptr[N] = E;
    __syncthreads();
    for (int i = lo + t; i < hi; i += 256) {
        unsigned int u = ebuk[i];
        int dl = u >> 16;
        int r = atomicAdd(&c[dl], 1);
        csr_src[rp[dl] + r] = (unsigned short)(u & 0xFFFF);
    }
}

// ---- fused per-layer kernel: gather-aggregate (fp8) -> LDS -> MFMA ------
// Phase 1: 8 x 32-lane groups aggregate the block's 64 rows into sA
// (bf16, stride 136). Phase 2: dual-GEMM MFMA with A-frags from LDS.
// C/D layout (m89): col=lane&15, row=(lane>>4)*4+reg.

__device__ __forceinline__ void acc_f8(float& x, float& y, float& z, float& w,
                                       unsigned int v) {
    f32x2 lo = __builtin_amdgcn_cvt_pk_f32_fp8(v, false);
    f32x2 hi = __builtin_amdgcn_cvt_pk_f32_fp8(v, true);
    x += lo.x; y += lo.y; z += hi.x; w += hi.y;
}

__device__ __forceinline__ void gather_rows_to_lds(const unsigned int* __restrict__ h8,
                                                   const int* __restrict__ row_ptr,
                                                   const unsigned short* __restrict__ csr_src,
                                                   const float* __restrict__ inv_cnt,
                                                   unsigned short* __restrict__ sA,
                                                   int row0, int t, int N) {
    int g32 = t >> 5, l = t & 31;
    for (int ni = g32; ni < 64; ni += 8) {
        int node = row0 + ni;
        ushort4 o = make_ushort4(0, 0, 0, 0);
        if (node < N) {
            int beg = row_ptr[node], end = row_ptr[node + 1];
            float a0x = 0.f, a0y = 0.f, a0z = 0.f, a0w = 0.f;
            float a1x = 0.f, a1y = 0.f, a1z = 0.f, a1w = 0.f;
            for (int base = beg; base < end; base += 32) {
                int idx = 0;
                if (base + l < end) idx = csr_src[base + l];
                int n = min(32, end - base);
                int j = 0;
                for (; j + 8 <= n; j += 8) {
                    int s0 = __shfl(idx, j + 0, 32);
                    int s1 = __shfl(idx, j + 1, 32);
                    int s2 = __shfl(idx, j + 2, 32);
                    int s3 = __shfl(idx, j + 3, 32);
                    int s4 = __shfl(idx, j + 4, 32);
                    int s5 = __shfl(idx, j + 5, 32);
                    int s6 = __shfl(idx, j + 6, 32);
                    int s7 = __shfl(idx, j + 7, 32);
                    unsigned int v0 = h8[(size_t)s0 * 32 + l];
                    unsigned int v1 = h8[(size_t)s1 * 32 + l];
                    unsigned int v2 = h8[(size_t)s2 * 32 + l];
                    unsigned int v3 = h8[(size_t)s3 * 32 + l];
                    unsigned int v4 = h8[(size_t)s4 * 32 + l];
                    unsigned int v5 = h8[(size_t)s5 * 32 + l];
                    unsigned int v6 = h8[(size_t)s6 * 32 + l];
                    unsigned int v7 = h8[(size_t)s7 * 32 + l];
                    acc_f8(a0x, a0y, a0z, a0w, v0);
                    acc_f8(a1x, a1y, a1z, a1w, v1);
                    acc_f8(a0x, a0y, a0z, a0w, v2);
                    acc_f8(a1x, a1y, a1z, a1w, v3);
                    acc_f8(a0x, a0y, a0z, a0w, v4);
                    acc_f8(a1x, a1y, a1z, a1w, v5);
                    acc_f8(a0x, a0y, a0z, a0w, v6);
                    acc_f8(a1x, a1y, a1z, a1w, v7);
                }
                for (; j < n; ++j) {
                    int s = __shfl(idx, j, 32);
                    acc_f8(a0x, a0y, a0z, a0w, h8[(size_t)s * 32 + l]);
                }
            }
            float iv = inv_cnt[node];
            o.x = f2bf((a0x + a1x) * iv);
            o.y = f2bf((a0y + a1y) * iv);
            o.z = f2bf((a0z + a1z) * iv);
            o.w = f2bf((a0w + a1w) * iv);
        }
        *(ushort4*)(sA + ni * SH_STRIDE + l * 4) = o;
    }
}

__global__ __launch_bounds__(256) void sage_fused_kernel(const unsigned int* __restrict__ h8,
                                                         const unsigned short* __restrict__ xb,
                                                         const int* __restrict__ row_ptr,
                                                         const unsigned short* __restrict__ csr_src,
                                                         const float* __restrict__ inv_cnt,
                                                         const unsigned short* __restrict__ wlp,
                                                         const unsigned short* __restrict__ wrp,
                                                         const float* __restrict__ bl,
                                                         unsigned short* __restrict__ outb,
                                                         unsigned char* __restrict__ out8,
                                                         int N) {
    __shared__ unsigned short sA[64 * SH_STRIDE];   // 17.4 KB
    int t = threadIdx.x;
    int row0 = blockIdx.x * 64;

    gather_rows_to_lds(h8, row_ptr, csr_src, inv_cnt, sA, row0, t, N);
    __syncthreads();

    int w = t >> 6;
    int l = t & 63;
    int rlo = l & 15;
    int khi = l >> 4;
    int wrow0 = row0 + w * 16;
    int rowA = wrow0 + rlo;
    bool okA = rowA < N;

    f32x4 acc[8];
    #pragma unroll
    for (int n = 0; n < 8; ++n) {
        float b = bl[n * 16 + rlo];
        acc[n] = (f32x4){b, b, b, b};
    }

    const unsigned short* Ar = sA + (w * 16 + rlo) * SH_STRIDE + khi * 8;
    const short* Xp = (const short*)xb + (size_t)(okA ? rowA : 0) * D + khi * 8;
    const short* WL = (const short*)wlp + l * 8;
    const short* WR = (const short*)wrp + l * 8;
    const bf16x8 Z = {0, 0, 0, 0, 0, 0, 0, 0};

    #pragma unroll 1
    for (int ks = 0; ks < 4; ++ks) {
        bf16x8 a = *(const bf16x8*)(Ar + ks * 32);
        #pragma unroll
        for (int n = 0; n < 8; ++n) {
            bf16x8 b = *(const bf16x8*)(WL + (ks * 8 + n) * 512);
            acc[n] = __builtin_amdgcn_mfma_f32_16x16x32_bf16(a, b, acc[n], 0, 0, 0);
        }
    }
    #pragma unroll 1
    for (int ks = 0; ks < 4; ++ks) {
        bf16x8 a = okA ? *(const bf16x8*)(Xp + ks * 32) : Z;
        #pragma unroll
        for (int n = 0; n < 8; ++n) {
            bf16x8 b = *(const bf16x8*)(WR + (ks * 8 + n) * 512);
            acc[n] = __builtin_amdgcn_mfma_f32_16x16x32_bf16(a, b, acc[n], 0, 0, 0);
        }
    }

    #pragma unroll
    for (int r = 0; r < 4; ++r) {
        float s = 0.f;
        #pragma unroll
        for (int n = 0; n < 8; ++n) s += acc[n][r] * acc[n][r];
        s += __shfl_xor(s, 1);
        s += __shfl_xor(s, 2);
        s += __shfl_xor(s, 4);
        s += __shfl_xor(s, 8);
        float inv = 1.0f / fmaxf(sqrtf(s), 1e-12f);
        int gr = wrow0 + khi * 4 + r;
        if (gr < N) {
            #pragma unroll
            for (int n = 0; n < 8; ++n) {
                float v = fmaxf(acc[n][r] * inv, 0.f);
                outb[(size_t)gr * D + n * 16 + rlo] = f2bf(v);
                out8[(size_t)gr * D + n * 16 + rlo] = f2f8(v);
            }
        }
    }
}

// ---- layer 3: gather + MFMA + norm + MFMA FC + softmax ------------------
// sA reused for h3 (wave-local rows, no extra sync needed after K loop).

__global__ __launch_bounds__(256) void sage_fused_fc_kernel(const unsigned int* __restrict__ h8,
                                                            const unsigned short* __restrict__ xb,
                                                            const int* __restrict__ row_ptr,
                                                            const unsigned short* __restrict__ csr_src,
                                                            const float* __restrict__ inv_cnt,
                                                            const unsigned short* __restrict__ wlp,
                                                            const unsigned short* __restrict__ wrp,
                                                            const float* __restrict__ bl,
                                                            const unsigned short* __restrict__ wfcp,
                                                            const float* __restrict__ bfc,
                                                            float* __restrict__ out, int N) {
    __shared__ unsigned short sA[64 * SH_STRIDE];   // 17.4 KB (agg, then h3)
    int t = threadIdx.x;
    int row0 = blockIdx.x * 64;

    gather_rows_to_lds(h8, row_ptr, csr_src, inv_cnt, sA, row0, t, N);
    __syncthreads();

    int w = t >> 6;
    int l = t & 63;
    int rlo = l & 15;
    int khi = l >> 4;
    int wrow0 = row0 + w * 16;
    int rowA = wrow0 + rlo;
    bool okA = rowA < N;

    f32x4 acc[8];
    #pragma unroll
    for (int n = 0; n < 8; ++n) {
        float b = bl[n * 16 + rlo];
        acc[n] = (f32x4){b, b, b, b};
    }

    const unsigned short* Ar = sA + (w * 16 + rlo) * SH_STRIDE + khi * 8;
    const short* Xp = (const short*)xb + (size_t)(okA ? rowA : 0) * D + khi * 8;
    const short* WL = (const short*)wlp + l * 8;
    const short* WR = (const short*)wrp + l * 8;
    const bf16x8 Z = {0, 0, 0, 0, 0, 0, 0, 0};

    #pragma unroll 1
    for (int ks = 0; ks < 4; ++ks) {
        bf16x8 a = *(const bf16x8*)(Ar + ks * 32);
        #pragma unroll
        for (int n = 0; n < 8; ++n) {
            bf16x8 b = *(const bf16x8*)(WL + (ks * 8 + n) * 512);
            acc[n] = __builtin_amdgcn_mfma_f32_16x16x32_bf16(a, b, acc[n], 0, 0, 0);
        }
    }
    #pragma unroll 1
    for (int ks = 0; ks < 4; ++ks) {
        bf16x8 a = okA ? *(const bf16x8*)(Xp + ks * 32) : Z;
        #pragma unroll
        for (int n = 0; n < 8; ++n) {
            bf16x8 b = *(const bf16x8*)(WR + (ks * 8 + n) * 512);
            acc[n] = __builtin_amdgcn_mfma_f32_16x16x32_bf16(a, b, acc[n], 0, 0, 0);
        }
    }

    // norm (no relu) -> overwrite sA rows (wave-local: this wave's A-frag
    // reads are complete; rows [w*16, w*16+16) are only touched by wave w)
    #pragma unroll
    for (int r = 0; r < 4; ++r) {
        float s = 0.f;
        #pragma unroll
        for (int n = 0; n < 8; ++n) s += acc[n][r] * acc[n][r];
        s += __shfl_xor(s, 1);
        s += __shfl_xor(s, 2);
        s += __shfl_xor(s, 4);
        s += __shfl_xor(s, 8);
        float inv = 1.0f / fmaxf(sqrtf(s), 1e-12f);
        int lr = w * 16 + khi * 4 + r;
        #pragma unroll
        for (int n = 0; n < 8; ++n)
            sA[lr * SH_STRIDE + n * 16 + rlo] = f2bf(acc[n][r] * inv);
    }

    // FC: A-frag from sA rows, B = packed Wfc (48 cols, >=40 zeroed)
    f32x4 fa[3];
    #pragma unroll
    for (int n = 0; n < 3; ++n) {
        int col = n * 16 + rlo;
        float b = (col < 40) ? bfc[col] : 0.f;
        fa[n] = (f32x4){b, b, b, b};
    }
    const short* WF = (const short*)wfcp + l * 8;
    const unsigned short* hrow = sA + (w * 16 + rlo) * SH_STRIDE + khi * 8;
    #pragma unroll
    for (int ks = 0; ks < 4; ++ks) {
        bf16x8 a = *(const bf16x8*)(hrow + ks * 32);
        #pragma unroll
        for (int n = 0; n < 3; ++n) {
            bf16x8 b = *(const bf16x8*)(WF + (ks * 3 + n) * 512);
            fa[n] = __builtin_amdgcn_mfma_f32_16x16x32_bf16(a, b, fa[n], 0, 0, 0);
        }
    }

    // softmax per row over 40 valid cols
    bool v2 = (rlo < 8);
    #pragma unroll
    for (int r = 0; r < 4; ++r) {
        float m = fmaxf(fa[0][r], fa[1][r]);
        if (v2) m = fmaxf(m, fa[2][r]);
        m = fmaxf(m, __shfl_xor(m, 1));
        m = fmaxf(m, __shfl_xor(m, 2));
        m = fmaxf(m, __shfl_xor(m, 4));
        m = fmaxf(m, __shfl_xor(m, 8));
        float e0 = expf(fa[0][r] - m);
        float e1 = expf(fa[1][r] - m);
        float e2 = v2 ? expf(fa[2][r] - m) : 0.f;
        float s = e0 + e1 + e2;
        s += __shfl_xor(s, 1);
        s += __shfl_xor(s, 2);
        s += __shfl_xor(s, 4);
        s += __shfl_xor(s, 8);
        float inv = 1.0f / s;
        int gr = wrow0 + khi * 4 + r;
        if (gr < N) {
            out[(size_t)gr * 40 + rlo]      = e0 * inv;
            out[(size_t)gr * 40 + 16 + rlo] = e1 * inv;
            if (v2) out[(size_t)gr * 40 + 32 + rlo] = e2 * inv;
        }
    }
}

// ---- launcher -----------------------------------------------------------

extern "C" void kernel_launch(void* const* d_in, const int* in_sizes, int n_in,
                              void* d_out, int out_size, void* d_ws, size_t ws_size,
                              hipStream_t stream) {
    const float* x   = (const float*)d_in[0];
    const int*   e   = (const int*)d_in[1];
    const float* W1l = (const float*)d_in[2];
    const float* b1  = (const float*)d_in[3];
    const float* W1r = (const float*)d_in[4];
    const float* W2l = (const float*)d_in[5];
    const float* b2  = (const float*)d_in[6];
    const float* W2r = (const float*)d_in[7];
    const float* W3l = (const float*)d_in[8];
    const float* b3  = (const float*)d_in[9];
    const float* W3r = (const float*)d_in[10];
    const float* Wfc = (const float*)d_in[11];
    const float* bfc = (const float*)d_in[12];
    float* out = (float*)d_out;

    const int N = NN;
    const int E = in_sizes[1] / 2;

    unsigned char* p = (unsigned char*)d_ws;
    unsigned short* xb   = (unsigned short*)p; p += (size_t)N * D * 2;
    unsigned short* h1b  = (unsigned short*)p; p += (size_t)N * D * 2;
    unsigned short* h2b  = (unsigned short*)p; p += (size_t)N * D * 2;
    unsigned char*  xf8  = (unsigned char*)p;  p += (size_t)N * D;   // reused as h2f8
    unsigned char*  h1f8 = (unsigned char*)p;  p += (size_t)N * D;
    unsigned short* wpk  = (unsigned short*)p; p += 6 * 16384 * 2;
    unsigned short* wfcp = (unsigned short*)p; p += 6144 * 2;
    float* inv_cnt = (float*)p; p += (size_t)N * 4;
    int* row_ptr = (int*)p; p += (size_t)(N + 4) * 4;
    int* bukcnt  = (int*)p; p += NBUK * 4;
    int* bukbase = (int*)p; p += (NBUK + 4) * 4;
    int* bukfill = (int*)p; p += NBUK * 4;
    unsigned int* ebuk = (unsigned int*)p; p += (size_t)E * 4;
    unsigned short* csr_src = (unsigned short*)p;
    unsigned char* h2f8 = xf8;   // xf8 dead after layer-1 gather

    unsigned short* w1lp = wpk;
    unsigned short* w1rp = wpk + 16384;
    unsigned short* w2lp = wpk + 2 * 16384;
    unsigned short* w2rp = wpk + 3 * 16384;
    unsigned short* w3lp = wpk + 4 * 16384;
    unsigned short* w3rp = wpk + 5 * 16384;

    int n4 = N * D / 4;
    cvtpack_kernel<<<408 + (n4 + 255) / 256, 256, 0, stream>>>(
        x, xb, (unsigned int*)xf8, n4, W1l, W1r, W2l, W2r, W3l, W3r, wpk,
        Wfc, wfcp, bukcnt);

    int EB = (E + EPB - 1) / EPB;
    bucket_hist_kernel<<<EB, 256, 0, stream>>>(e, E, bukcnt);
    bucket_scan_kernel<<<1, 256, 0, stream>>>(bukcnt, bukbase, bukfill, E);
    bucket_scatter_kernel<<<EB, 256, 0, stream>>>(e, E, bukfill, ebuk);
    cnt_scan_scatter_kernel<<<NBUK, 256, 0, stream>>>(ebuk, bukbase, row_ptr,
                                                      inv_cnt, csr_src, N, E);

    int sageBlocks = (N + 63) / 64;

    sage_fused_kernel<<<sageBlocks, 256, 0, stream>>>(
        (const unsigned int*)xf8, xb, row_ptr, csr_src, inv_cnt,
        w1lp, w1rp, b1, h1b, h1f8, N);

    sage_fused_kernel<<<sageBlocks, 256, 0, stream>>>(
        (const unsigned int*)h1f8, h1b, row_ptr, csr_src, inv_cnt,
        w2lp, w2rp, b2, h2b, h2f8, N);

    sage_fused_fc_kernel<<<sageBlocks, 256, 0, stream>>>(
        (const unsigned int*)h2f8, h2b, row_ptr, csr_src, inv_cnt,
        w3lp, w3rp, b3, wfcp, bfc, out, N);
}

// Round 19
// 168.454 us; speedup vs baseline: 1.1053x; 1.1053x over previous
//
#include <hip/hip_runtime.h>
#include <math.h>

#define NN 50000
#define D 128
#define NBUK 256   // dst buckets (dst>>8), covers 65536 >= N
#define EPB 4096   // edges per block in bucket passes
#define SH_STRIDE 136

typedef __attribute__((ext_vector_type(8))) short bf16x8;
typedef __attribute__((ext_vector_type(4))) float f32x4;
typedef __attribute__((ext_vector_type(2))) float f32x2;

__device__ __forceinline__ float bf2f(unsigned short u) {
    union { unsigned int i; float f; } c;
    c.i = ((unsigned int)u) << 16;
    return c.f;
}
__device__ __forceinline__ unsigned short f2bf(float f) {
    union { float f; unsigned int i; } c;
    c.f = f;
    unsigned int u = c.i;
    return (unsigned short)((u + 0x7FFFu + ((u >> 16) & 1u)) >> 16);
}
__device__ __forceinline__ unsigned char f2f8(float v) {
    return (unsigned char)(__builtin_amdgcn_cvt_pk_fp8_f32(v, v, 0, false) & 0xFF);
}

// ---- merged: weight pack + Wfc pack + x cvt + edge bucket-hist ----------
// blocks [0,384): layer weights; [384,408): Wfc; [408,6658): x convert;
// [6658, 6658+EB): per-block LDS histogram of dst>>8 (bukcnt pre-zeroed).

__global__ __launch_bounds__(256) void cvtpack_kernel(const float* __restrict__ x,
                                                      unsigned short* __restrict__ xb,
                                                      unsigned int* __restrict__ x8,
                                                      int n4,
                                                      const float* __restrict__ W0,
                                                      const float* __restrict__ W1,
                                                      const float* __restrict__ W2,
                                                      const float* __restrict__ W3,
                                                      const float* __restrict__ W4,
                                                      const float* __restrict__ W5,
                                                      unsigned short* __restrict__ P,
                                                      const float* __restrict__ Wfc,
                                                      unsigned short* __restrict__ Pfc,
                                                      const int* __restrict__ e, int E,
                                                      int* __restrict__ bukcnt,
                                                      int xblocks) {
    if (blockIdx.x < 384) {
        int i = blockIdx.x * 256 + threadIdx.x;
        int w = i >> 14, j = i & 16383;
        const float* W = (w == 0) ? W0 : (w == 1) ? W1 : (w == 2) ? W2
                       : (w == 3) ? W3 : (w == 4) ? W4 : W5;
        int el = j & 7, l = (j >> 3) & 63, n = (j >> 9) & 7, ks = j >> 12;
        int k = ks * 32 + (l >> 4) * 8 + el;
        int col = n * 16 + (l & 15);
        P[i] = f2bf(W[k * D + col]);
    } else if (blockIdx.x < 408) {
        int i = (blockIdx.x - 384) * 256 + threadIdx.x;
        int el = i & 7, l = (i >> 3) & 63, f = i >> 9;
        int ks = f / 3, n = f - ks * 3;
        int k = ks * 32 + (l >> 4) * 8 + el;
        int col = n * 16 + (l & 15);
        Pfc[i] = (col < 40) ? f2bf(Wfc[k * 40 + col]) : (unsigned short)0;
    } else if (blockIdx.x < 408 + xblocks) {
        int i = (blockIdx.x - 408) * 256 + threadIdx.x;
        if (i < n4) {
            float4 v = ((const float4*)x)[i];
            ushort4 o;
            o.x = f2bf(v.x); o.y = f2bf(v.y); o.z = f2bf(v.z); o.w = f2bf(v.w);
            ((ushort4*)xb)[i] = o;
            unsigned int p01 = __builtin_amdgcn_cvt_pk_fp8_f32(v.x, v.y, 0, false);
            unsigned int p23 = __builtin_amdgcn_cvt_pk_fp8_f32(v.z, v.w, 0, false);
            x8[i] = (p01 & 0xFFFFu) | (p23 << 16);
        }
    } else {
        __shared__ int h[NBUK];
        int t = threadIdx.x;
        h[t] = 0;
        __syncthreads();
        int base = (blockIdx.x - 408 - xblocks) * EPB;
        #pragma unroll
        for (int k = 0; k < 4; ++k) {
            int idx = base + k * 1024 + t * 4;
            if (idx + 4 <= E) {
                int4 d = *(const int4*)(e + E + idx);
                atomicAdd(&h[d.x >> 8], 1);
                atomicAdd(&h[d.y >> 8], 1);
                atomicAdd(&h[d.z >> 8], 1);
                atomicAdd(&h[d.w >> 8], 1);
            } else {
                for (int i = idx; i < E; ++i) atomicAdd(&h[e[E + i] >> 8], 1);
            }
        }
        __syncthreads();
        if (h[t]) atomicAdd(&bukcnt[t], h[t]);
    }
}

// ---- bucketed CSR build -------------------------------------------------

__global__ __launch_bounds__(256) void bucket_scan_kernel(const int* __restrict__ bukcnt,
                                                          int* __restrict__ bukbase,
                                                          int* __restrict__ bukfill, int E) {
    __shared__ int wsum[4], woff[4];
    int t = threadIdx.x;
    int lane = t & 63, wave = t >> 6;
    int v = bukcnt[t];
    int incl = v;
    for (int off = 1; off < 64; off <<= 1) {
        int u = __shfl_up(incl, off);
        if (lane >= off) incl += u;
    }
    if (lane == 63) wsum[wave] = incl;
    __syncthreads();
    if (t == 0) {
        int r = 0;
        #pragma unroll
        for (int w = 0; w < 4; ++w) { woff[w] = r; r += wsum[w]; }
    }
    __syncthreads();
    int excl = woff[wave] + incl - v;
    bukbase[t] = excl;
    bukfill[t] = excl;
    if (t == 255) bukbase[NBUK] = E;
}

__global__ __launch_bounds__(256) void bucket_scatter_kernel(const int* __restrict__ e, int E,
                                                             int* __restrict__ bukfill,
                                                             unsigned int* __restrict__ ebuk) {
    __shared__ int h[NBUK];
    __shared__ int res[NBUK];
    int t = threadIdx.x;
    h[t] = 0;
    __syncthreads();
    int base = blockIdx.x * EPB;
    int4 d[4];
    #pragma unroll
    for (int k = 0; k < 4; ++k) {
        int idx = base + k * 1024 + t * 4;
        if (idx + 4 <= E) {
            d[k] = *(const int4*)(e + E + idx);
        } else {
            d[k].x = (idx + 0 < E) ? e[E + idx + 0] : -1;
            d[k].y = (idx + 1 < E) ? e[E + idx + 1] : -1;
            d[k].z = (idx + 2 < E) ? e[E + idx + 2] : -1;
            d[k].w = (idx + 3 < E) ? e[E + idx + 3] : -1;
        }
        if (d[k].x >= 0) atomicAdd(&h[d[k].x >> 8], 1);
        if (d[k].y >= 0) atomicAdd(&h[d[k].y >> 8], 1);
        if (d[k].z >= 0) atomicAdd(&h[d[k].z >> 8], 1);
        if (d[k].w >= 0) atomicAdd(&h[d[k].w >> 8], 1);
    }
    __syncthreads();
    res[t] = h[t] ? atomicAdd(&bukfill[t], h[t]) : 0;
    h[t] = 0;
    __syncthreads();
    #pragma unroll
    for (int k = 0; k < 4; ++k) {
        int idx = base + k * 1024 + t * 4;
        int4 s;
        if (idx + 4 <= E) {
            s = *(const int4*)(e + idx);
        } else {
            s.x = (idx + 0 < E) ? e[idx + 0] : 0;
            s.y = (idx + 1 < E) ? e[idx + 1] : 0;
            s.z = (idx + 2 < E) ? e[idx + 2] : 0;
            s.w = (idx + 3 < E) ? e[idx + 3] : 0;
        }
        if (d[k].x >= 0) { int b = d[k].x >> 8; int r = atomicAdd(&h[b], 1);
            ebuk[res[b] + r] = (unsigned int)(s.x & 0xFFFF) | ((unsigned int)(d[k].x & 255) << 16); }
        if (d[k].y >= 0) { int b = d[k].y >> 8; int r = atomicAdd(&h[b], 1);
            ebuk[res[b] + r] = (unsigned int)(s.y & 0xFFFF) | ((unsigned int)(d[k].y & 255) << 16); }
        if (d[k].z >= 0) { int b = d[k].z >> 8; int r = atomicAdd(&h[b], 1);
            ebuk[res[b] + r] = (unsigned int)(s.z & 0xFFFF) | ((unsigned int)(d[k].z & 255) << 16); }
        if (d[k].w >= 0) { int b = d[k].w >> 8; int r = atomicAdd(&h[b], 1);
            ebuk[res[b] + r] = (unsigned int)(s.w & 0xFFFF) | ((unsigned int)(d[k].w & 255) << 16); }
    }
}

// fused: per-bucket histogram + scan -> row_ptr/inv_cnt, then scatter
// csr_src using the in-LDS row pointers (same block = same bucket).

__global__ __launch_bounds__(256) void cnt_scan_scatter_kernel(const unsigned int* __restrict__ ebuk,
                                                               const int* __restrict__ bukbase,
                                                               int* __restrict__ row_ptr,
                                                               float* __restrict__ inv_cnt,
                                                               unsigned short* __restrict__ csr_src,
                                                               int N, int E) {
    __shared__ int c[NBUK];
    __shared__ int rp[NBUK];
    __shared__ int wsum[4], woff[4];
    int t = threadIdx.x, b = blockIdx.x;
    c[t] = 0;
    __syncthreads();
    int lo = bukbase[b], hi = bukbase[b + 1];
    for (int i = lo + t; i < hi; i += 256) atomicAdd(&c[ebuk[i] >> 16], 1);
    __syncthreads();
    int v = c[t];
    int lane = t & 63, wave = t >> 6;
    int incl = v;
    for (int off = 1; off < 64; off <<= 1) {
        int u = __shfl_up(incl, off);
        if (lane >= off) incl += u;
    }
    if (lane == 63) wsum[wave] = incl;
    __syncthreads();
    if (t == 0) {
        int r = 0;
        #pragma unroll
        for (int w = 0; w < 4; ++w) { woff[w] = r; r += wsum[w]; }
    }
    __syncthreads();
    int excl = woff[wave] + incl - v;
    rp[t] = bukbase[b] + excl;
    c[t] = 0;   // reuse as per-node fill counter
    int g = b * NBUK + t;
    if (g < N) {
        row_ptr[g] = rp[t];
        inv_cnt[g] = 1.0f / fmaxf((float)v, 1.0f);
    }
    if (g == N) row_ptr[N] = E;
    __syncthreads();
    for (int i = lo + t; i < hi; i += 256) {
        unsigned int u = ebuk[i];
        int dl = u >> 16;
        int r = atomicAdd(&c[dl], 1);
        csr_src[rp[dl] + r] = (unsigned short)(u & 0xFFFF);
    }
}

// ---- mean aggregation over fp8 rows: 32-lane group per node -------------

__device__ __forceinline__ void acc_f8(float& x, float& y, float& z, float& w,
                                       unsigned int v) {
    f32x2 lo = __builtin_amdgcn_cvt_pk_f32_fp8(v, false);
    f32x2 hi = __builtin_amdgcn_cvt_pk_f32_fp8(v, true);
    x += lo.x; y += lo.y; z += hi.x; w += hi.y;
}

__global__ __launch_bounds__(256) void aggregate_kernel(const unsigned int* __restrict__ h8,
                                                        const int* __restrict__ row_ptr,
                                                        const unsigned short* __restrict__ csr_src,
                                                        const float* __restrict__ inv_cnt,
                                                        unsigned short* __restrict__ agg, int N) {
    int node = (int)((blockIdx.x * blockDim.x + threadIdx.x) >> 5);
    int l = threadIdx.x & 31;
    if (node >= N) return;
    int beg = row_ptr[node], end = row_ptr[node + 1];
    float a0x = 0.f, a0y = 0.f, a0z = 0.f, a0w = 0.f;
    float a1x = 0.f, a1y = 0.f, a1z = 0.f, a1w = 0.f;
    for (int base = beg; base < end; base += 32) {
        int idx = 0;
        if (base + l < end) idx = csr_src[base + l];
        int n = min(32, end - base);
        int j = 0;
        for (; j + 8 <= n; j += 8) {
            int s0 = __shfl(idx, j + 0, 32);
            int s1 = __shfl(idx, j + 1, 32);
            int s2 = __shfl(idx, j + 2, 32);
            int s3 = __shfl(idx, j + 3, 32);
            int s4 = __shfl(idx, j + 4, 32);
            int s5 = __shfl(idx, j + 5, 32);
            int s6 = __shfl(idx, j + 6, 32);
            int s7 = __shfl(idx, j + 7, 32);
            unsigned int v0 = h8[(size_t)s0 * 32 + l];
            unsigned int v1 = h8[(size_t)s1 * 32 + l];
            unsigned int v2 = h8[(size_t)s2 * 32 + l];
            unsigned int v3 = h8[(size_t)s3 * 32 + l];
            unsigned int v4 = h8[(size_t)s4 * 32 + l];
            unsigned int v5 = h8[(size_t)s5 * 32 + l];
            unsigned int v6 = h8[(size_t)s6 * 32 + l];
            unsigned int v7 = h8[(size_t)s7 * 32 + l];
            acc_f8(a0x, a0y, a0z, a0w, v0);
            acc_f8(a1x, a1y, a1z, a1w, v1);
            acc_f8(a0x, a0y, a0z, a0w, v2);
            acc_f8(a1x, a1y, a1z, a1w, v3);
            acc_f8(a0x, a0y, a0z, a0w, v4);
            acc_f8(a1x, a1y, a1z, a1w, v5);
            acc_f8(a0x, a0y, a0z, a0w, v6);
            acc_f8(a1x, a1y, a1z, a1w, v7);
        }
        for (; j < n; ++j) {
            int s = __shfl(idx, j, 32);
            acc_f8(a0x, a0y, a0z, a0w, h8[(size_t)s * 32 + l]);
        }
    }
    float iv = inv_cnt[node];
    ushort4 o;
    o.x = f2bf((a0x + a1x) * iv);
    o.y = f2bf((a0y + a1y) * iv);
    o.z = f2bf((a0z + a1z) * iv);
    o.w = f2bf((a0w + a1w) * iv);
    ((ushort4*)agg)[(size_t)node * 32 + l] = o;
}

// ---- MFMA dual-GEMM + bias + L2-normalize + ReLU (layers 1-2) -----------
// C/D layout (m89): col=lane&15, row=(lane>>4)*4+reg.

__global__ __launch_bounds__(256) void sage_mfma_kernel(const unsigned short* __restrict__ aggb,
                                                        const unsigned short* __restrict__ xb,
                                                        const unsigned short* __restrict__ wlp,
                                                        const unsigned short* __restrict__ wrp,
                                                        const float* __restrict__ bl,
                                                        unsigned short* __restrict__ outb,
                                                        unsigned char* __restrict__ out8,
                                                        int N) {
    int t = threadIdx.x;
    int w = t >> 6;
    int l = t & 63;
    int rlo = l & 15;
    int khi = l >> 4;
    int row0 = blockIdx.x * 64 + w * 16;
    int rowA = row0 + rlo;
    bool okA = rowA < N;

    f32x4 acc[8];
    #pragma unroll
    for (int n = 0; n < 8; ++n) {
        float b = bl[n * 16 + rlo];
        acc[n] = (f32x4){b, b, b, b};
    }

    const short* Ap = (const short*)aggb + (size_t)(okA ? rowA : 0) * D + khi * 8;
    const short* Xp = (const short*)xb   + (size_t)(okA ? rowA : 0) * D + khi * 8;
    const short* WL = (const short*)wlp + l * 8;
    const short* WR = (const short*)wrp + l * 8;
    const bf16x8 Z = {0, 0, 0, 0, 0, 0, 0, 0};

    #pragma unroll 1
    for (int ks = 0; ks < 4; ++ks) {
        bf16x8 a = okA ? *(const bf16x8*)(Ap + ks * 32) : Z;
        #pragma unroll
        for (int n = 0; n < 8; ++n) {
            bf16x8 b = *(const bf16x8*)(WL + (ks * 8 + n) * 512);
            acc[n] = __builtin_amdgcn_mfma_f32_16x16x32_bf16(a, b, acc[n], 0, 0, 0);
        }
    }
    #pragma unroll 1
    for (int ks = 0; ks < 4; ++ks) {
        bf16x8 a = okA ? *(const bf16x8*)(Xp + ks * 32) : Z;
        #pragma unroll
        for (int n = 0; n < 8; ++n) {
            bf16x8 b = *(const bf16x8*)(WR + (ks * 8 + n) * 512);
            acc[n] = __builtin_amdgcn_mfma_f32_16x16x32_bf16(a, b, acc[n], 0, 0, 0);
        }
    }

    #pragma unroll
    for (int r = 0; r < 4; ++r) {
        float s = 0.f;
        #pragma unroll
        for (int n = 0; n < 8; ++n) s += acc[n][r] * acc[n][r];
        s += __shfl_xor(s, 1);
        s += __shfl_xor(s, 2);
        s += __shfl_xor(s, 4);
        s += __shfl_xor(s, 8);
        float inv = 1.0f / fmaxf(sqrtf(s), 1e-12f);
        int gr = row0 + khi * 4 + r;
        if (gr < N) {
            #pragma unroll
            for (int n = 0; n < 8; ++n) {
                float v = fmaxf(acc[n][r] * inv, 0.f);
                outb[(size_t)gr * D + n * 16 + rlo] = f2bf(v);
                out8[(size_t)gr * D + n * 16 + rlo] = f2f8(v);
            }
        }
    }
}

// ---- layer 3 fused: MFMA dual-GEMM + norm + MFMA FC + softmax -----------

__global__ __launch_bounds__(256) void sage_mfma_fc_kernel(const unsigned short* __restrict__ aggb,
                                                           const unsigned short* __restrict__ xb,
                                                           const unsigned short* __restrict__ wlp,
                                                           const unsigned short* __restrict__ wrp,
                                                           const float* __restrict__ bl,
                                                           const unsigned short* __restrict__ wfcp,
                                                           const float* __restrict__ bfc,
                                                           float* __restrict__ out, int N) {
    __shared__ unsigned short sH[64 * SH_STRIDE];   // 17.4 KB, bf16 h3
    int t = threadIdx.x;
    int w = t >> 6;
    int l = t & 63;
    int rlo = l & 15;
    int khi = l >> 4;
    int row0 = blockIdx.x * 64 + w * 16;
    int rowA = row0 + rlo;
    bool okA = rowA < N;

    f32x4 acc[8];
    #pragma unroll
    for (int n = 0; n < 8; ++n) {
        float b = bl[n * 16 + rlo];
        acc[n] = (f32x4){b, b, b, b};
    }

    const short* Ap = (const short*)aggb + (size_t)(okA ? rowA : 0) * D + khi * 8;
    const short* Xp = (const short*)xb   + (size_t)(okA ? rowA : 0) * D + khi * 8;
    const short* WL = (const short*)wlp + l * 8;
    const short* WR = (const short*)wrp + l * 8;
    const bf16x8 Z = {0, 0, 0, 0, 0, 0, 0, 0};

    #pragma unroll 1
    for (int ks = 0; ks < 4; ++ks) {
        bf16x8 a = okA ? *(const bf16x8*)(Ap + ks * 32) : Z;
        #pragma unroll
        for (int n = 0; n < 8; ++n) {
            bf16x8 b = *(const bf16x8*)(WL + (ks * 8 + n) * 512);
            acc[n] = __builtin_amdgcn_mfma_f32_16x16x32_bf16(a, b, acc[n], 0, 0, 0);
        }
    }
    #pragma unroll 1
    for (int ks = 0; ks < 4; ++ks) {
        bf16x8 a = okA ? *(const bf16x8*)(Xp + ks * 32) : Z;
        #pragma unroll
        for (int n = 0; n < 8; ++n) {
            bf16x8 b = *(const bf16x8*)(WR + (ks * 8 + n) * 512);
            acc[n] = __builtin_amdgcn_mfma_f32_16x16x32_bf16(a, b, acc[n], 0, 0, 0);
        }
    }

    // norm (no relu) -> wave-local LDS rows as bf16
    #pragma unroll
    for (int r = 0; r < 4; ++r) {
        float s = 0.f;
        #pragma unroll
        for (int n = 0; n < 8; ++n) s += acc[n][r] * acc[n][r];
        s += __shfl_xor(s, 1);
        s += __shfl_xor(s, 2);
        s += __shfl_xor(s, 4);
        s += __shfl_xor(s, 8);
        float inv = 1.0f / fmaxf(sqrtf(s), 1e-12f);
        int lr = w * 16 + khi * 4 + r;
        #pragma unroll
        for (int n = 0; n < 8; ++n)
            sH[lr * SH_STRIDE + n * 16 + rlo] = f2bf(acc[n][r] * inv);
    }
    // wave-local rows: no __syncthreads needed.

    f32x4 fa[3];
    #pragma unroll
    for (int n = 0; n < 3; ++n) {
        int col = n * 16 + rlo;
        float b = (col < 40) ? bfc[col] : 0.f;
        fa[n] = (f32x4){b, b, b, b};
    }
    const short* WF = (const short*)wfcp + l * 8;
    const unsigned short* hrow = sH + (w * 16 + rlo) * SH_STRIDE + khi * 8;
    #pragma unroll
    for (int ks = 0; ks < 4; ++ks) {
        bf16x8 a = *(const bf16x8*)(hrow + ks * 32);
        #pragma unroll
        for (int n = 0; n < 3; ++n) {
            bf16x8 b = *(const bf16x8*)(WF + (ks * 3 + n) * 512);
            fa[n] = __builtin_amdgcn_mfma_f32_16x16x32_bf16(a, b, fa[n], 0, 0, 0);
        }
    }

    bool v2 = (rlo < 8);
    #pragma unroll
    for (int r = 0; r < 4; ++r) {
        float m = fmaxf(fa[0][r], fa[1][r]);
        if (v2) m = fmaxf(m, fa[2][r]);
        m = fmaxf(m, __shfl_xor(m, 1));
        m = fmaxf(m, __shfl_xor(m, 2));
        m = fmaxf(m, __shfl_xor(m, 4));
        m = fmaxf(m, __shfl_xor(m, 8));
        float e0 = expf(fa[0][r] - m);
        float e1 = expf(fa[1][r] - m);
        float e2 = v2 ? expf(fa[2][r] - m) : 0.f;
        float s = e0 + e1 + e2;
        s += __shfl_xor(s, 1);
        s += __shfl_xor(s, 2);
        s += __shfl_xor(s, 4);
        s += __shfl_xor(s, 8);
        float inv = 1.0f / s;
        int gr = row0 + khi * 4 + r;
        if (gr < N) {
            out[(size_t)gr * 40 + rlo]      = e0 * inv;
            out[(size_t)gr * 40 + 16 + rlo] = e1 * inv;
            if (v2) out[(size_t)gr * 40 + 32 + rlo] = e2 * inv;
        }
    }
}

// ---- launcher -----------------------------------------------------------

extern "C" void kernel_launch(void* const* d_in, const int* in_sizes, int n_in,
                              void* d_out, int out_size, void* d_ws, size_t ws_size,
                              hipStream_t stream) {
    const float* x   = (const float*)d_in[0];
    const int*   e   = (const int*)d_in[1];
    const float* W1l = (const float*)d_in[2];
    const float* b1  = (const float*)d_in[3];
    const float* W1r = (const float*)d_in[4];
    const float* W2l = (const float*)d_in[5];
    const float* b2  = (const float*)d_in[6];
    const float* W2r = (const float*)d_in[7];
    const float* W3l = (const float*)d_in[8];
    const float* b3  = (const float*)d_in[9];
    const float* W3r = (const float*)d_in[10];
    const float* Wfc = (const float*)d_in[11];
    const float* bfc = (const float*)d_in[12];
    float* out = (float*)d_out;

    const int N = NN;
    const int E = in_sizes[1] / 2;

    unsigned char* p = (unsigned char*)d_ws;
    unsigned short* xb   = (unsigned short*)p; p += (size_t)N * D * 2;
    unsigned short* h1b  = (unsigned short*)p; p += (size_t)N * D * 2;
    unsigned short* h2b  = (unsigned short*)p; p += (size_t)N * D * 2;
    unsigned short* aggb = (unsigned short*)p; p += (size_t)N * D * 2;
    unsigned char*  xf8  = (unsigned char*)p;  p += (size_t)N * D;   // reused as h2f8
    unsigned char*  h1f8 = (unsigned char*)p;  p += (size_t)N * D;
    unsigned short* wpk  = (unsigned short*)p; p += 6 * 16384 * 2;
    unsigned short* wfcp = (unsigned short*)p; p += 6144 * 2;
    float* inv_cnt = (float*)p; p += (size_t)N * 4;
    int* row_ptr = (int*)p; p += (size_t)(N + 4) * 4;
    int* bukcnt  = (int*)p; p += NBUK * 4;
    int* bukbase = (int*)p; p += (NBUK + 4) * 4;
    int* bukfill = (int*)p; p += NBUK * 4;
    unsigned int* ebuk = (unsigned int*)p; p += (size_t)E * 4;
    unsigned short* csr_src = (unsigned short*)p;
    unsigned char* h2f8 = xf8;   // xf8 dead after layer-1 aggregate

    unsigned short* w1lp = wpk;
    unsigned short* w1rp = wpk + 16384;
    unsigned short* w2lp = wpk + 2 * 16384;
    unsigned short* w2rp = wpk + 3 * 16384;
    unsigned short* w3lp = wpk + 4 * 16384;
    unsigned short* w3rp = wpk + 5 * 16384;

    hipMemsetAsync(bukcnt, 0, sizeof(int) * NBUK, stream);

    int n4 = N * D / 4;
    int xblocks = (n4 + 255) / 256;
    int EB = (E + EPB - 1) / EPB;
    cvtpack_kernel<<<408 + xblocks + EB, 256, 0, stream>>>(
        x, xb, (unsigned int*)xf8, n4, W1l, W1r, W2l, W2r, W3l, W3r, wpk,
        Wfc, wfcp, e, E, bukcnt, xblocks);

    bucket_scan_kernel<<<1, 256, 0, stream>>>(bukcnt, bukbase, bukfill, E);
    bucket_scatter_kernel<<<EB, 256, 0, stream>>>(e, E, bukfill, ebuk);
    cnt_scan_scatter_kernel<<<NBUK, 256, 0, stream>>>(ebuk, bukbase, row_ptr,
                                                      inv_cnt, csr_src, N, E);

    int aggBlocks = (N * 32 + 255) / 256;
    int sageBlocks = (N + 63) / 64;

    aggregate_kernel<<<aggBlocks, 256, 0, stream>>>((const unsigned int*)xf8, row_ptr,
                                                    csr_src, inv_cnt, aggb, N);
    sage_mfma_kernel<<<sageBlocks, 256, 0, stream>>>(aggb, xb, w1lp, w1rp, b1,
                                                     h1b, h1f8, N);

    aggregate_kernel<<<aggBlocks, 256, 0, stream>>>((const unsigned int*)h1f8, row_ptr,
                                                    csr_src, inv_cnt, aggb, N);
    sage_mfma_kernel<<<sageBlocks, 256, 0, stream>>>(aggb, h1b, w2lp, w2rp, b2,
                                                     h2b, h2f8, N);

    aggregate_kernel<<<aggBlocks, 256, 0, stream>>>((const unsigned int*)h2f8, row_ptr,
                                                    csr_src, inv_cnt, aggb, N);
    sage_mfma_fc_kernel<<<sageBlocks, 256, 0, stream>>>(aggb, h2b, w3lp, w3rp, b3,
                                                        wfcp, bfc, out, N);
}